// Round 15
// baseline (561.771 us; speedup 1.0000x reference)
//
#include <hip/hip_runtime.h>

#define N_NODES  100000
#define N_EDGES  1600000
#define DIM      128
#define N_GRAPHS 512

#define BW       512                         // nodes per bucket
#define NBUCK    ((N_NODES + BW - 1) / BW)   // 196
#define CAP      12288                       // max edges per bucket (avg 8163, +45 sigma)
#define NB_CHUNK 4096

typedef short  bf16x8 __attribute__((ext_vector_type(8)));
typedef float  f32x4  __attribute__((ext_vector_type(4)));

__device__ inline ushort f2bf(float f) {  // round-to-nearest-even
    union { float f; unsigned u; } v; v.f = f;
    unsigned r = v.u + 0x7FFFu + ((v.u >> 16) & 1u);
    return (ushort)(r >> 16);
}
__device__ inline float bf2f_lo(unsigned u) { union { unsigned u; float f; } v; v.u = u << 16; return v.f; }
__device__ inline float bf2f_hi(unsigned u) { union { unsigned u; float f; } v; v.u = u & 0xFFFF0000u; return v.f; }

// ---------------- dtype conversion ----------------

// xb[i] = bf16( x[i] * dinv[node] )  -- prescaled layer-0 input (row-major)
__global__ __launch_bounds__(256) void cvt_x(const float* __restrict__ x,
                                             const float* __restrict__ dinv,
                                             ushort* __restrict__ xb) {
    int i = (blockIdx.x * 256 + threadIdx.x) * 4;  // 12.8M elements, exact
    float d = dinv[i >> 7];
    float4 v = *(const float4*)(x + i);
    ushort4 o;
    o.x = f2bf(v.x * d); o.y = f2bf(v.y * d); o.z = f2bf(v.z * d); o.w = f2bf(v.w * d);
    *(ushort4*)(xb + i) = o;
}

// WT[L][n][k] = Ws[L][k][n], bf16
__global__ __launch_bounds__(256) void cvt_w(const float* __restrict__ Ws,
                                             ushort* __restrict__ WT) {
    int idx = blockIdx.x * 256 + threadIdx.x;  // 65536 total
    int L = idx >> 14, n = (idx >> 7) & 127, k = idx & 127;
    WT[idx] = f2bf(Ws[(L << 14) + (k << 7) + n]);
}

// ---------------- CSR build via LDS-staged bucket sort ----------------

__global__ __launch_bounds__(256) void initb_kernel(int* __restrict__ bfill,
                                                    int* __restrict__ csr) {
    int t = threadIdx.x;
    if (t < NBUCK) bfill[t] = t * CAP;
    if (t == 255) csr[N_NODES] = N_EDGES;
}

// 1024 threads: 4 edges/thread; scan section runs on t<256 with uniform barriers
__global__ __launch_bounds__(1024) void bin_kernel(const int* __restrict__ row,
                                                   const int* __restrict__ col,
                                                   int* __restrict__ bfill,
                                                   unsigned* __restrict__ tmp) {
    __shared__ unsigned s_val[NB_CHUNK];
    __shared__ int s_dst[NB_CHUNK];
    __shared__ int s_hist[256], s_scan[256];
    __shared__ int s_excl[NBUCK], s_base[NBUCK], s_cur[NBUCK];
    int t = threadIdx.x;
    int e0 = blockIdx.x * NB_CHUNK;

    if (t < 256) s_hist[t] = 0;
    __syncthreads();
#pragma unroll
    for (int k = 0; k < 4; ++k) {
        int e = e0 + t + k * 1024;
        if (e < N_EDGES) atomicAdd(&s_hist[col[e] >> 9], 1);
    }
    __syncthreads();
    int h = 0;
    if (t < 256) { h = s_hist[t]; s_scan[t] = h; }
    __syncthreads();
    for (int o = 1; o < 256; o <<= 1) {
        int u = 0;
        if (t < 256 && t >= o) u = s_scan[t - o];
        __syncthreads();
        if (t < 256) s_scan[t] += u;
        __syncthreads();
    }
    if (t < NBUCK) {
        int ex = s_scan[t] - h;
        s_excl[t] = ex;
        s_cur[t]  = ex;
        s_base[t] = atomicAdd(&bfill[t], h);
    }
    __syncthreads();
#pragma unroll
    for (int k = 0; k < 4; ++k) {
        int e = e0 + t + k * 1024;
        if (e < N_EDGES) {
            int r = row[e], c = col[e];
            int b = c >> 9;
            int p = atomicAdd(&s_cur[b], 1);
            int dst = s_base[b] + (p - s_excl[b]);
            int lim = (b + 1) * CAP;
            if (dst >= lim) dst = lim - 1;  // overflow clamp (statistically impossible)
            s_val[p] = ((unsigned)(c & (BW - 1)) << 17) | (unsigned)r;
            s_dst[p] = dst;
        }
    }
    __syncthreads();
    int sc = N_EDGES - e0; if (sc > NB_CHUNK) sc = NB_CHUNK;
#pragma unroll
    for (int k = 0; k < 4; ++k) {
        int j = t + k * 1024;
        if (j < sc) tmp[s_dst[j]] = s_val[j];
    }
}

__global__ __launch_bounds__(256) void bscan_kernel(const int* __restrict__ bfill,
                                                    int* __restrict__ bbase) {
    __shared__ int s[256];
    int t = threadIdx.x;
    int cnt = 0;
    if (t < NBUCK) {
        cnt = bfill[t] - t * CAP;
        if (cnt > CAP) cnt = CAP;
    }
    s[t] = cnt;
    __syncthreads();
    for (int o = 1; o < 256; o <<= 1) {
        int u = (t >= o) ? s[t - o] : 0;
        __syncthreads();
        s[t] += u;
        __syncthreads();
    }
    if (t < NBUCK) bbase[t] = s[t] - cnt;
}

// 1024 threads: count/scatter/flush 4x wider; pair-scan on t<256
__global__ __launch_bounds__(1024) void sort_kernel(const unsigned* __restrict__ tmp,
                                                    const int* __restrict__ bfill,
                                                    const int* __restrict__ bbase,
                                                    int* __restrict__ csr,
                                                    float* __restrict__ dinv,
                                                    int* __restrict__ ssrc) {
    __shared__ int s_cnt[BW];
    __shared__ int s_pair[256];
    __shared__ int s_off[BW];
    __shared__ int s_cur[BW];
    __shared__ int s_stage[CAP];
    int b = blockIdx.x, t = threadIdx.x;
    int wbeg = b * BW;
    int wn = N_NODES - wbeg; if (wn > BW) wn = BW;
    int nE = bfill[b] - b * CAP; if (nE > CAP) nE = CAP;
    const unsigned* T = tmp + (size_t)b * CAP;
    int base = bbase[b];

    for (int i = t; i < BW; i += 1024) s_cnt[i] = 0;
    __syncthreads();
    for (int i = t; i < nE; i += 1024) atomicAdd(&s_cnt[T[i] >> 17], 1);
    __syncthreads();
    int a0 = 0, a1 = 0;
    if (t < 256) { a0 = s_cnt[2 * t]; a1 = s_cnt[2 * t + 1]; s_pair[t] = a0 + a1; }
    __syncthreads();
    for (int o = 1; o < 256; o <<= 1) {
        int u = 0;
        if (t < 256 && t >= o) u = s_pair[t - o];
        __syncthreads();
        if (t < 256) s_pair[t] += u;
        __syncthreads();
    }
    if (t < 256) {
        int pre = s_pair[t] - (a0 + a1);
        s_off[2 * t] = pre;      s_off[2 * t + 1] = pre + a0;
        s_cur[2 * t] = pre;      s_cur[2 * t + 1] = pre + a0;
    }
    __syncthreads();
    for (int i = t; i < wn; i += 1024) {
        csr[wbeg + i]  = base + s_off[i];
        dinv[wbeg + i] = rsqrtf((float)(s_cnt[i] + 1));  // +1 = self loop
    }
    for (int i = t; i < nE; i += 1024) {
        unsigned v = T[i];
        int p = atomicAdd(&s_cur[v >> 17], 1);
        s_stage[p] = (int)(v & 0x1FFFFu);
    }
    __syncthreads();
    for (int i = t; i < nE; i += 1024) ssrc[base + i] = s_stage[i];
}

__global__ __launch_bounds__(256) void bounds_kernel(const int* __restrict__ batch,
                                                     int* __restrict__ gstart) {
    int i = blockIdx.x * 256 + threadIdx.x;
    if (i >= N_NODES) return;
    int b  = batch[i];
    int bp = (i == 0) ? -1 : batch[i - 1];
    for (int g = bp + 1; g <= b; ++g) gstart[g] = i;
    if (i == N_NODES - 1) {
        for (int g = b + 1; g <= N_GRAPHS; ++g) gstart[g] = N_NODES;
    }
}

// ---------------- fused layer: aggregate (to LDS) + MFMA GEMM ----------------
// 512 thr / 8 waves; wave owns 16 nodes; ZERO barriers (all wave-local).
// Phase 1: quarter-wave gathers write bf16 rows into the wave's private sA
// (swizzled chunks: phys = (chunk+row)&15). LDS = 32 KB total -> 4 blocks/CU
// = 32 waves/CU. Phase 2: 32 MFMAs; A-frags from sA, B-frags DIRECT FROM
// GLOBAL WT (32 KB, L2-resident, shared by all blocks). Epilogue restaged
// through sA -> coalesced 256 B row stores. NOTE: in/out MUST be distinct
// buffers (ping-pong) — blocks gather from rows other blocks write.
#define ACC8(vv) do { \
    acc[0] += bf2f_lo((vv).x); acc[1] += bf2f_hi((vv).x); \
    acc[2] += bf2f_lo((vv).y); acc[3] += bf2f_hi((vv).y); \
    acc[4] += bf2f_lo((vv).z); acc[5] += bf2f_hi((vv).z); \
    acc[6] += bf2f_lo((vv).w); acc[7] += bf2f_hi((vv).w); } while (0)

__global__ __launch_bounds__(512) void layer_kernel(const ushort* __restrict__ g,
                                                    const ushort* __restrict__ WT,
                                                    const float* __restrict__ bias,
                                                    const float* __restrict__ dinv,
                                                    const int* __restrict__ csr,
                                                    const int* __restrict__ ssrc,
                                                    ushort* __restrict__ out,
                                                    int mode) {
    __shared__ ushort sA[8][16 * 128];      // per-wave, swizzled; 32 KB
    int t = threadIdx.x;
    int m0blk = blockIdx.x * 128;

    int wv   = t >> 6;
    int lane = t & 63;
    int q    = lane >> 4;
    int l    = lane & 15;
    int mw   = m0blk + wv * 16;
    ushort* sAw = sA[wv];
    const uint4* hp = (const uint4*)g;

    // ---- phase 1: aggregate 4 nodes per quarter-wave into sA ----
#pragma unroll 1
    for (int i = 0; i < 4; ++i) {
        int row  = q * 4 + i;
        int node = mw + row;
        float acc[8];
#pragma unroll
        for (int z = 0; z < 8; ++z) acc[z] = 0.f;
        if (node < N_NODES) {
            uint4 v = hp[(size_t)node * 16 + l];
            acc[0] = bf2f_lo(v.x); acc[1] = bf2f_hi(v.x);
            acc[2] = bf2f_lo(v.y); acc[3] = bf2f_hi(v.y);
            acc[4] = bf2f_lo(v.z); acc[5] = bf2f_hi(v.z);
            acc[6] = bf2f_lo(v.w); acc[7] = bf2f_hi(v.w);
            int e = csr[node], end = csr[node + 1];
            for (; e + 3 < end; e += 4) {
                int s0 = ssrc[e], s1 = ssrc[e + 1], s2 = ssrc[e + 2], s3 = ssrc[e + 3];
                uint4 v0 = hp[(size_t)s0 * 16 + l];
                uint4 v1 = hp[(size_t)s1 * 16 + l];
                uint4 v2 = hp[(size_t)s2 * 16 + l];
                uint4 v3 = hp[(size_t)s3 * 16 + l];
                ACC8(v0); ACC8(v1); ACC8(v2); ACC8(v3);
            }
            if (e + 1 < end) {
                int s0 = ssrc[e], s1 = ssrc[e + 1];
                uint4 v0 = hp[(size_t)s0 * 16 + l];
                uint4 v1 = hp[(size_t)s1 * 16 + l];
                ACC8(v0); ACC8(v1);
                e += 2;
            }
            if (e < end) {
                int s = ssrc[e];
                uint4 v1 = hp[(size_t)s * 16 + l];
                ACC8(v1);
            }
            float d = dinv[node];
#pragma unroll
            for (int z = 0; z < 8; ++z) acc[z] *= d;
        }
        uint4 ov;
        ov.x = (uint)f2bf(acc[0]) | ((uint)f2bf(acc[1]) << 16);
        ov.y = (uint)f2bf(acc[2]) | ((uint)f2bf(acc[3]) << 16);
        ov.z = (uint)f2bf(acc[4]) | ((uint)f2bf(acc[5]) << 16);
        ov.w = (uint)f2bf(acc[6]) | ((uint)f2bf(acc[7]) << 16);
        *(uint4*)(sAw + row * 128 + ((l + row) & 15) * 8) = ov;
    }

    // ---- phase 2: wave-local MFMA; B-frags from global WT (L2-hot) ----
    f32x4 facc[8];
#pragma unroll
    for (int n = 0; n < 8; ++n) facc[n] = (f32x4){0.f, 0.f, 0.f, 0.f};
#pragma unroll
    for (int ki = 0; ki < 4; ++ki) {
        int ca = ki * 4 + q;  // A chunk for this lane (row = l)
        bf16x8 a = *(const bf16x8*)(sAw + l * 128 + ((ca + l) & 15) * 8);
#pragma unroll
        for (int n = 0; n < 8; ++n) {
            bf16x8 b = *(const bf16x8*)(WT + (size_t)(n * 16 + l) * 128 + ki * 32 + q * 8);
            facc[n] = __builtin_amdgcn_mfma_f32_16x16x32_bf16(a, b, facc[n], 0, 0, 0);
        }
    }

    // ---- epilogue: restage into sAw, then coalesced flush ----
    {
        int lr0 = q * 4;  // C/D: local row = q*4 + reg, col = n*16 + l
        float sc[4];
#pragma unroll
        for (int r = 0; r < 4; ++r) {
            int m = mw + lr0 + r;
            sc[r] = (mode && m < N_NODES) ? dinv[m] : 1.0f;
        }
#pragma unroll
        for (int n = 0; n < 8; ++n) {
            int col = n * 16 + l;
            float bv = bias[col];
            int c = col >> 3;
#pragma unroll
            for (int r = 0; r < 4; ++r) {
                int lr = lr0 + r;
                float v = facc[n][r] + bv;
                if (mode) v = fmaxf(v, 0.f) * sc[r];
                sAw[lr * 128 + ((c + lr) & 15) * 8 + (col & 7)] = f2bf(v);
            }
        }
    }
#pragma unroll
    for (int j = 0; j < 4; ++j) {
        int idx = lane + j * 64;
        int lr = idx >> 4, c = idx & 15;
        int m = mw + lr;
        if (m < N_NODES) {
            uint4 v = *(const uint4*)(sAw + lr * 128 + ((c + lr) & 15) * 8);
            *(uint4*)(out + (size_t)m * 128 + c * 8) = v;
        }
    }
}

// ---------------- fused pooling + MLP head (one block per graph) -------------

__global__ __launch_bounds__(256) void pool_mlp(const ushort* __restrict__ h,
                                                const int* __restrict__ gstart,
                                                const float* __restrict__ w1,
                                                const float* __restrict__ b1,
                                                const float* __restrict__ w2,
                                                const float* __restrict__ b2,
                                                float* __restrict__ out) {
    __shared__ float part[4][128];
    __shared__ float mean[128];
    __shared__ float hid[100];
    int g = blockIdx.x;
    int s = gstart[g], e2 = gstart[g + 1];
    int p     = threadIdx.x & 63;
    int which = threadIdx.x >> 6;
    const uint* hu = (const uint*)h;

    float a0 = 0.f, a1 = 0.f;
    for (int n = s + which; n < e2; n += 4) {
        uint v = hu[(size_t)n * 64 + p];
        a0 += bf2f_lo(v);
        a1 += bf2f_hi(v);
    }
    part[which][2 * p]     = a0;
    part[which][2 * p + 1] = a1;
    __syncthreads();
    if (which == 0) {
        float c = fmaxf((float)(e2 - s), 1.0f);
        mean[2 * p]     = (part[0][2 * p] + part[1][2 * p] + part[2][2 * p] + part[3][2 * p]) / c;
        mean[2 * p + 1] = (part[0][2 * p + 1] + part[1][2 * p + 1] + part[2][2 * p + 1] + part[3][2 * p + 1]) / c;
    }
    __syncthreads();
    int t = threadIdx.x;
    if (t < 100) {
        float s1 = b1[t];
        for (int k = 0; k < 128; ++k) s1 = fmaf(mean[k], w1[k * 100 + t], s1);
        hid[t] = fmaxf(s1, 0.f);
    }
    __syncthreads();
    if (t < 4) {
        float s2 = b2[t];
        for (int j = 0; j < 100; ++j) s2 = fmaf(hid[j], w2[j * 4 + t], s2);
        out[(size_t)g * 4 + t] = s2;
    }
}

// ---------------- launch ----------------

extern "C" void kernel_launch(void* const* d_in, const int* in_sizes, int n_in,
                              void* d_out, int out_size, void* d_ws, size_t ws_size,
                              hipStream_t stream) {
    const float* x   = (const float*)d_in[0];
    const float* Ws  = (const float*)d_in[1];
    const float* bs  = (const float*)d_in[2];
    const float* w1  = (const float*)d_in[3];
    const float* b1  = (const float*)d_in[4];
    const float* w2  = (const float*)d_in[5];
    const float* b2  = (const float*)d_in[6];
    const int*   ei  = (const int*)d_in[7];
    const int*   bat = (const int*)d_in[8];
    float* outp = (float*)d_out;

    char* p = (char*)d_ws;
    auto take = [&](size_t bytes) -> void* {
        void* r = (void*)p;
        p += (bytes + 255) & ~(size_t)255;
        return r;
    };
    int*      csr    = (int*)take((size_t)(N_NODES + 1) * 4);
    float*    dinv   = (float*)take((size_t)N_NODES * 4);
    int*      bfill  = (int*)take((size_t)NBUCK * 4);
    int*      bbase  = (int*)take((size_t)NBUCK * 4);
    unsigned* tmp    = (unsigned*)take((size_t)NBUCK * CAP * 4);
    int*      ssrc   = (int*)take((size_t)N_EDGES * 4);
    ushort*   xb     = (ushort*)take((size_t)N_NODES * 128 * 2);
    ushort*   hbA    = (ushort*)take((size_t)N_NODES * 128 * 2);
    ushort*   hbB    = (ushort*)take((size_t)N_NODES * 128 * 2);
    ushort*   WT     = (ushort*)take((size_t)4 * 128 * 128 * 2);
    int*      gstart = (int*)take((size_t)(N_GRAPHS + 1) * 4);

    const int* row = ei;
    const int* col = ei + N_EDGES;

    initb_kernel<<<1, 256, 0, stream>>>(bfill, csr);
    bin_kernel<<<(N_EDGES + NB_CHUNK - 1) / NB_CHUNK, 1024, 0, stream>>>(row, col, bfill, tmp);
    bscan_kernel<<<1, 256, 0, stream>>>(bfill, bbase);
    sort_kernel<<<NBUCK, 1024, 0, stream>>>(tmp, bfill, bbase, csr, dinv, ssrc);
    cvt_x<<<12500, 256, 0, stream>>>(x, dinv, xb);
    cvt_w<<<256, 256, 0, stream>>>(Ws, WT);
    bounds_kernel<<<(N_NODES + 255) / 256, 256, 0, stream>>>(bat, gstart);

    // ping-pong: layer input and output must be DISTINCT buffers (blocks
    // gather from rows other blocks write)
    const ushort* hin = xb;
    ushort* hout = hbA;
    for (int L = 0; L < 4; ++L) {
        layer_kernel<<<(N_NODES + 127) / 128, 512, 0, stream>>>(
            hin, WT + (size_t)L * 128 * 128, bs + (size_t)L * 128, dinv,
            csr, ssrc, hout, (L < 3) ? 1 : 0);
        hin = hout;
        hout = (hout == hbA) ? hbB : hbA;
    }
    // after 4 layers: hin points at the final output buffer
    pool_mlp<<<N_GRAPHS, 256, 0, stream>>>(hin, gstart, w1, b1, w2, b2, outp);
}

// Round 16
// 456.430 us; speedup vs baseline: 1.2308x; 1.2308x over previous
//
#include <hip/hip_runtime.h>

#define N_NODES  100000
#define N_EDGES  1600000
#define DIM      128
#define N_GRAPHS 512

#define BW       512                         // nodes per bucket
#define NBUCK    ((N_NODES + BW - 1) / BW)   // 196
#define CAP      12288                       // max edges per bucket (avg 8163, +45 sigma)
#define NB_CHUNK 4096

typedef short  bf16x8 __attribute__((ext_vector_type(8)));
typedef float  f32x4  __attribute__((ext_vector_type(4)));

__device__ inline ushort f2bf(float f) {  // round-to-nearest-even
    union { float f; unsigned u; } v; v.f = f;
    unsigned r = v.u + 0x7FFFu + ((v.u >> 16) & 1u);
    return (ushort)(r >> 16);
}
__device__ inline float bf2f_lo(unsigned u) { union { unsigned u; float f; } v; v.u = u << 16; return v.f; }
__device__ inline float bf2f_hi(unsigned u) { union { unsigned u; float f; } v; v.u = u & 0xFFFF0000u; return v.f; }

// ---------------- dtype conversion ----------------

// xb[i] = bf16( x[i] * dinv[node] )  -- prescaled layer-0 input (row-major)
__global__ __launch_bounds__(256) void cvt_x(const float* __restrict__ x,
                                             const float* __restrict__ dinv,
                                             ushort* __restrict__ xb) {
    int i = (blockIdx.x * 256 + threadIdx.x) * 4;  // 12.8M elements, exact
    float d = dinv[i >> 7];
    float4 v = *(const float4*)(x + i);
    ushort4 o;
    o.x = f2bf(v.x * d); o.y = f2bf(v.y * d); o.z = f2bf(v.z * d); o.w = f2bf(v.w * d);
    *(ushort4*)(xb + i) = o;
}

// WT[L][n][k] = Ws[L][k][n], bf16
__global__ __launch_bounds__(256) void cvt_w(const float* __restrict__ Ws,
                                             ushort* __restrict__ WT) {
    int idx = blockIdx.x * 256 + threadIdx.x;  // 65536 total
    int L = idx >> 14, n = (idx >> 7) & 127, k = idx & 127;
    WT[idx] = f2bf(Ws[(L << 14) + (k << 7) + n]);
}

// ---------------- CSR build via LDS-staged bucket sort ----------------

__global__ __launch_bounds__(256) void initb_kernel(int* __restrict__ bfill,
                                                    int* __restrict__ csr) {
    int t = threadIdx.x;
    if (t < NBUCK) bfill[t] = t * CAP;
    if (t == 255) csr[N_NODES] = N_EDGES;
}

// 1024 threads: 4 edges/thread; scan section runs on t<256 with uniform barriers
__global__ __launch_bounds__(1024) void bin_kernel(const int* __restrict__ row,
                                                   const int* __restrict__ col,
                                                   int* __restrict__ bfill,
                                                   unsigned* __restrict__ tmp) {
    __shared__ unsigned s_val[NB_CHUNK];
    __shared__ int s_dst[NB_CHUNK];
    __shared__ int s_hist[256], s_scan[256];
    __shared__ int s_excl[NBUCK], s_base[NBUCK], s_cur[NBUCK];
    int t = threadIdx.x;
    int e0 = blockIdx.x * NB_CHUNK;

    if (t < 256) s_hist[t] = 0;
    __syncthreads();
#pragma unroll
    for (int k = 0; k < 4; ++k) {
        int e = e0 + t + k * 1024;
        if (e < N_EDGES) atomicAdd(&s_hist[col[e] >> 9], 1);
    }
    __syncthreads();
    int h = 0;
    if (t < 256) { h = s_hist[t]; s_scan[t] = h; }
    __syncthreads();
    for (int o = 1; o < 256; o <<= 1) {
        int u = 0;
        if (t < 256 && t >= o) u = s_scan[t - o];
        __syncthreads();
        if (t < 256) s_scan[t] += u;
        __syncthreads();
    }
    if (t < NBUCK) {
        int ex = s_scan[t] - h;
        s_excl[t] = ex;
        s_cur[t]  = ex;
        s_base[t] = atomicAdd(&bfill[t], h);
    }
    __syncthreads();
#pragma unroll
    for (int k = 0; k < 4; ++k) {
        int e = e0 + t + k * 1024;
        if (e < N_EDGES) {
            int r = row[e], c = col[e];
            int b = c >> 9;
            int p = atomicAdd(&s_cur[b], 1);
            int dst = s_base[b] + (p - s_excl[b]);
            int lim = (b + 1) * CAP;
            if (dst >= lim) dst = lim - 1;  // overflow clamp (statistically impossible)
            s_val[p] = ((unsigned)(c & (BW - 1)) << 17) | (unsigned)r;
            s_dst[p] = dst;
        }
    }
    __syncthreads();
    int sc = N_EDGES - e0; if (sc > NB_CHUNK) sc = NB_CHUNK;
#pragma unroll
    for (int k = 0; k < 4; ++k) {
        int j = t + k * 1024;
        if (j < sc) tmp[s_dst[j]] = s_val[j];
    }
}

__global__ __launch_bounds__(256) void bscan_kernel(const int* __restrict__ bfill,
                                                    int* __restrict__ bbase) {
    __shared__ int s[256];
    int t = threadIdx.x;
    int cnt = 0;
    if (t < NBUCK) {
        cnt = bfill[t] - t * CAP;
        if (cnt > CAP) cnt = CAP;
    }
    s[t] = cnt;
    __syncthreads();
    for (int o = 1; o < 256; o <<= 1) {
        int u = (t >= o) ? s[t - o] : 0;
        __syncthreads();
        s[t] += u;
        __syncthreads();
    }
    if (t < NBUCK) bbase[t] = s[t] - cnt;
}

// 1024 threads: count/scatter/flush 4x wider; pair-scan on t<256
__global__ __launch_bounds__(1024) void sort_kernel(const unsigned* __restrict__ tmp,
                                                    const int* __restrict__ bfill,
                                                    const int* __restrict__ bbase,
                                                    int* __restrict__ csr,
                                                    float* __restrict__ dinv,
                                                    int* __restrict__ ssrc) {
    __shared__ int s_cnt[BW];
    __shared__ int s_pair[256];
    __shared__ int s_off[BW];
    __shared__ int s_cur[BW];
    __shared__ int s_stage[CAP];
    int b = blockIdx.x, t = threadIdx.x;
    int wbeg = b * BW;
    int wn = N_NODES - wbeg; if (wn > BW) wn = BW;
    int nE = bfill[b] - b * CAP; if (nE > CAP) nE = CAP;
    const unsigned* T = tmp + (size_t)b * CAP;
    int base = bbase[b];

    for (int i = t; i < BW; i += 1024) s_cnt[i] = 0;
    __syncthreads();
    for (int i = t; i < nE; i += 1024) atomicAdd(&s_cnt[T[i] >> 17], 1);
    __syncthreads();
    int a0 = 0, a1 = 0;
    if (t < 256) { a0 = s_cnt[2 * t]; a1 = s_cnt[2 * t + 1]; s_pair[t] = a0 + a1; }
    __syncthreads();
    for (int o = 1; o < 256; o <<= 1) {
        int u = 0;
        if (t < 256 && t >= o) u = s_pair[t - o];
        __syncthreads();
        if (t < 256) s_pair[t] += u;
        __syncthreads();
    }
    if (t < 256) {
        int pre = s_pair[t] - (a0 + a1);
        s_off[2 * t] = pre;      s_off[2 * t + 1] = pre + a0;
        s_cur[2 * t] = pre;      s_cur[2 * t + 1] = pre + a0;
    }
    __syncthreads();
    for (int i = t; i < wn; i += 1024) {
        csr[wbeg + i]  = base + s_off[i];
        dinv[wbeg + i] = rsqrtf((float)(s_cnt[i] + 1));  // +1 = self loop
    }
    for (int i = t; i < nE; i += 1024) {
        unsigned v = T[i];
        int p = atomicAdd(&s_cur[v >> 17], 1);
        s_stage[p] = (int)(v & 0x1FFFFu);
    }
    __syncthreads();
    for (int i = t; i < nE; i += 1024) ssrc[base + i] = s_stage[i];
}

__global__ __launch_bounds__(256) void bounds_kernel(const int* __restrict__ batch,
                                                     int* __restrict__ gstart) {
    int i = blockIdx.x * 256 + threadIdx.x;
    if (i >= N_NODES) return;
    int b  = batch[i];
    int bp = (i == 0) ? -1 : batch[i - 1];
    for (int g = bp + 1; g <= b; ++g) gstart[g] = i;
    if (i == N_NODES - 1) {
        for (int g = b + 1; g <= N_GRAPHS; ++g) gstart[g] = N_NODES;
    }
}

// ---------------- fused layer: aggregate (to LDS) + MFMA GEMM ----------------
// 512 thr / 8 waves; wave owns 16 nodes. sW staged in LDS (R14 form — R15
// proved global-WT B-frags regress). LDS = 64 KB -> 2 blocks/CU = 4 waves/
// SIMD, so VGPR budget/wave is 512: the 8-deep gather unroll is
// occupancy-free here (unlike R11's standalone agg). Phase 2 wave-local,
// one barrier total. in/out MUST be distinct (ping-pong).
#define ACC8(vv) do { \
    acc[0] += bf2f_lo((vv).x); acc[1] += bf2f_hi((vv).x); \
    acc[2] += bf2f_lo((vv).y); acc[3] += bf2f_hi((vv).y); \
    acc[4] += bf2f_lo((vv).z); acc[5] += bf2f_hi((vv).z); \
    acc[6] += bf2f_lo((vv).w); acc[7] += bf2f_hi((vv).w); } while (0)

__global__ __launch_bounds__(512) void layer_kernel(const ushort* __restrict__ g,
                                                    const ushort* __restrict__ WT,
                                                    const float* __restrict__ bias,
                                                    const float* __restrict__ dinv,
                                                    const int* __restrict__ csr,
                                                    const int* __restrict__ ssrc,
                                                    ushort* __restrict__ out,
                                                    int mode) {
    __shared__ ushort sW[128 * 128];        // swizzled
    __shared__ ushort sA[8][16 * 128];      // per-wave, swizzled
    int t = threadIdx.x;
    int m0blk = blockIdx.x * 128;

    {   // stage WT swizzled: 2048 uint4, 4 per thread
#pragma unroll
        for (int j = 0; j < 4; ++j) {
            int idx = t + j * 512;
            int r = idx >> 4, c = idx & 15;
            uint4 v = *(const uint4*)(WT + (size_t)r * 128 + c * 8);
            *(uint4*)(sW + r * 128 + ((c + r) & 15) * 8) = v;
        }
    }
    __syncthreads();

    int wv   = t >> 6;
    int lane = t & 63;
    int q    = lane >> 4;
    int l    = lane & 15;
    int mw   = m0blk + wv * 16;
    ushort* sAw = sA[wv];
    const uint4* hp = (const uint4*)g;

    // ---- phase 1: aggregate 4 nodes per quarter-wave into sA (8-deep) ----
#pragma unroll 1
    for (int i = 0; i < 4; ++i) {
        int row  = q * 4 + i;
        int node = mw + row;
        float acc[8];
#pragma unroll
        for (int z = 0; z < 8; ++z) acc[z] = 0.f;
        if (node < N_NODES) {
            uint4 v = hp[(size_t)node * 16 + l];
            acc[0] = bf2f_lo(v.x); acc[1] = bf2f_hi(v.x);
            acc[2] = bf2f_lo(v.y); acc[3] = bf2f_hi(v.y);
            acc[4] = bf2f_lo(v.z); acc[5] = bf2f_hi(v.z);
            acc[6] = bf2f_lo(v.w); acc[7] = bf2f_hi(v.w);
            int e = csr[node], end = csr[node + 1];
            for (; e + 7 < end; e += 8) {
                int s0 = ssrc[e],     s1 = ssrc[e + 1], s2 = ssrc[e + 2], s3 = ssrc[e + 3];
                int s4 = ssrc[e + 4], s5 = ssrc[e + 5], s6 = ssrc[e + 6], s7 = ssrc[e + 7];
                uint4 v0 = hp[(size_t)s0 * 16 + l];
                uint4 v1 = hp[(size_t)s1 * 16 + l];
                uint4 v2 = hp[(size_t)s2 * 16 + l];
                uint4 v3 = hp[(size_t)s3 * 16 + l];
                uint4 v4 = hp[(size_t)s4 * 16 + l];
                uint4 v5 = hp[(size_t)s5 * 16 + l];
                uint4 v6 = hp[(size_t)s6 * 16 + l];
                uint4 v7 = hp[(size_t)s7 * 16 + l];
                ACC8(v0); ACC8(v1); ACC8(v2); ACC8(v3);
                ACC8(v4); ACC8(v5); ACC8(v6); ACC8(v7);
            }
            for (; e + 1 < end; e += 2) {
                int s0 = ssrc[e], s1 = ssrc[e + 1];
                uint4 v0 = hp[(size_t)s0 * 16 + l];
                uint4 v1 = hp[(size_t)s1 * 16 + l];
                ACC8(v0); ACC8(v1);
            }
            if (e < end) {
                int s = ssrc[e];
                uint4 v1 = hp[(size_t)s * 16 + l];
                ACC8(v1);
            }
            float d = dinv[node];
#pragma unroll
            for (int z = 0; z < 8; ++z) acc[z] *= d;
        }
        uint4 ov;
        ov.x = (uint)f2bf(acc[0]) | ((uint)f2bf(acc[1]) << 16);
        ov.y = (uint)f2bf(acc[2]) | ((uint)f2bf(acc[3]) << 16);
        ov.z = (uint)f2bf(acc[4]) | ((uint)f2bf(acc[5]) << 16);
        ov.w = (uint)f2bf(acc[6]) | ((uint)f2bf(acc[7]) << 16);
        *(uint4*)(sAw + row * 128 + ((l + row) & 15) * 8) = ov;
    }

    // ---- phase 2: wave-local MFMA (A rows = this wave's 16 nodes) ----
    f32x4 facc[8];
#pragma unroll
    for (int n = 0; n < 8; ++n) facc[n] = (f32x4){0.f, 0.f, 0.f, 0.f};
#pragma unroll
    for (int ki = 0; ki < 4; ++ki) {
        int ca = ki * 4 + q;  // A chunk for this lane (row = l)
        bf16x8 a = *(const bf16x8*)(sAw + l * 128 + ((ca + l) & 15) * 8);
#pragma unroll
        for (int n = 0; n < 8; ++n) {
            int rB = n * 16 + l;
            bf16x8 b = *(const bf16x8*)(sW + rB * 128 + ((ca + rB) & 15) * 8);
            facc[n] = __builtin_amdgcn_mfma_f32_16x16x32_bf16(a, b, facc[n], 0, 0, 0);
        }
    }

    // ---- epilogue: restage into sAw, then coalesced flush ----
    {
        int lr0 = q * 4;  // C/D: local row = q*4 + reg, col = n*16 + l
        float sc[4];
#pragma unroll
        for (int r = 0; r < 4; ++r) {
            int m = mw + lr0 + r;
            sc[r] = (mode && m < N_NODES) ? dinv[m] : 1.0f;
        }
#pragma unroll
        for (int n = 0; n < 8; ++n) {
            int col = n * 16 + l;
            float bv = bias[col];
            int c = col >> 3;
#pragma unroll
            for (int r = 0; r < 4; ++r) {
                int lr = lr0 + r;
                float v = facc[n][r] + bv;
                if (mode) v = fmaxf(v, 0.f) * sc[r];
                sAw[lr * 128 + ((c + lr) & 15) * 8 + (col & 7)] = f2bf(v);
            }
        }
    }
#pragma unroll
    for (int j = 0; j < 4; ++j) {
        int idx = lane + j * 64;
        int lr = idx >> 4, c = idx & 15;
        int m = mw + lr;
        if (m < N_NODES) {
            uint4 v = *(const uint4*)(sAw + lr * 128 + ((c + lr) & 15) * 8);
            *(uint4*)(out + (size_t)m * 128 + c * 8) = v;
        }
    }
}

// ---------------- fused pooling + MLP head (one block per graph) -------------

__global__ __launch_bounds__(256) void pool_mlp(const ushort* __restrict__ h,
                                                const int* __restrict__ gstart,
                                                const float* __restrict__ w1,
                                                const float* __restrict__ b1,
                                                const float* __restrict__ w2,
                                                const float* __restrict__ b2,
                                                float* __restrict__ out) {
    __shared__ float part[4][128];
    __shared__ float mean[128];
    __shared__ float hid[100];
    int g = blockIdx.x;
    int s = gstart[g], e2 = gstart[g + 1];
    int p     = threadIdx.x & 63;
    int which = threadIdx.x >> 6;
    const uint* hu = (const uint*)h;

    float a0 = 0.f, a1 = 0.f;
    for (int n = s + which; n < e2; n += 4) {
        uint v = hu[(size_t)n * 64 + p];
        a0 += bf2f_lo(v);
        a1 += bf2f_hi(v);
    }
    part[which][2 * p]     = a0;
    part[which][2 * p + 1] = a1;
    __syncthreads();
    if (which == 0) {
        float c = fmaxf((float)(e2 - s), 1.0f);
        mean[2 * p]     = (part[0][2 * p] + part[1][2 * p] + part[2][2 * p] + part[3][2 * p]) / c;
        mean[2 * p + 1] = (part[0][2 * p + 1] + part[1][2 * p + 1] + part[2][2 * p + 1] + part[3][2 * p + 1]) / c;
    }
    __syncthreads();
    int t = threadIdx.x;
    if (t < 100) {
        float s1 = b1[t];
        for (int k = 0; k < 128; ++k) s1 = fmaf(mean[k], w1[k * 100 + t], s1);
        hid[t] = fmaxf(s1, 0.f);
    }
    __syncthreads();
    if (t < 4) {
        float s2 = b2[t];
        for (int j = 0; j < 100; ++j) s2 = fmaf(hid[j], w2[j * 4 + t], s2);
        out[(size_t)g * 4 + t] = s2;
    }
}

// ---------------- launch ----------------

extern "C" void kernel_launch(void* const* d_in, const int* in_sizes, int n_in,
                              void* d_out, int out_size, void* d_ws, size_t ws_size,
                              hipStream_t stream) {
    const float* x   = (const float*)d_in[0];
    const float* Ws  = (const float*)d_in[1];
    const float* bs  = (const float*)d_in[2];
    const float* w1  = (const float*)d_in[3];
    const float* b1  = (const float*)d_in[4];
    const float* w2  = (const float*)d_in[5];
    const float* b2  = (const float*)d_in[6];
    const int*   ei  = (const int*)d_in[7];
    const int*   bat = (const int*)d_in[8];
    float* outp = (float*)d_out;

    char* p = (char*)d_ws;
    auto take = [&](size_t bytes) -> void* {
        void* r = (void*)p;
        p += (bytes + 255) & ~(size_t)255;
        return r;
    };
    int*      csr    = (int*)take((size_t)(N_NODES + 1) * 4);
    float*    dinv   = (float*)take((size_t)N_NODES * 4);
    int*      bfill  = (int*)take((size_t)NBUCK * 4);
    int*      bbase  = (int*)take((size_t)NBUCK * 4);
    unsigned* tmp    = (unsigned*)take((size_t)NBUCK * CAP * 4);
    int*      ssrc   = (int*)take((size_t)N_EDGES * 4);
    ushort*   xb     = (ushort*)take((size_t)N_NODES * 128 * 2);
    ushort*   hbA    = (ushort*)take((size_t)N_NODES * 128 * 2);
    ushort*   hbB    = (ushort*)take((size_t)N_NODES * 128 * 2);
    ushort*   WT     = (ushort*)take((size_t)4 * 128 * 128 * 2);
    int*      gstart = (int*)take((size_t)(N_GRAPHS + 1) * 4);

    const int* row = ei;
    const int* col = ei + N_EDGES;

    initb_kernel<<<1, 256, 0, stream>>>(bfill, csr);
    bin_kernel<<<(N_EDGES + NB_CHUNK - 1) / NB_CHUNK, 1024, 0, stream>>>(row, col, bfill, tmp);
    bscan_kernel<<<1, 256, 0, stream>>>(bfill, bbase);
    sort_kernel<<<NBUCK, 1024, 0, stream>>>(tmp, bfill, bbase, csr, dinv, ssrc);
    cvt_x<<<12500, 256, 0, stream>>>(x, dinv, xb);
    cvt_w<<<256, 256, 0, stream>>>(Ws, WT);
    bounds_kernel<<<(N_NODES + 255) / 256, 256, 0, stream>>>(bat, gstart);

    // ping-pong: layer input and output must be DISTINCT buffers (blocks
    // gather from rows other blocks write)
    const ushort* hin = xb;
    ushort* hout = hbA;
    for (int L = 0; L < 4; ++L) {
        layer_kernel<<<(N_NODES + 127) / 128, 512, 0, stream>>>(
            hin, WT + (size_t)L * 128 * 128, bs + (size_t)L * 128, dinv,
            csr, ssrc, hout, (L < 3) ? 1 : 0);
        hin = hout;
        hout = (hout == hbA) ? hbB : hbA;
    }
    // after 4 layers: hin points at the final output buffer
    pool_mlp<<<N_GRAPHS, 256, 0, stream>>>(hin, gstart, w1, b1, w2, b2, outp);
}